// Round 7
// baseline (258.024 us; speedup 1.0000x reference)
//
#include <hip/hip_runtime.h>

#define T_DIM 4096
#define J_DIM 24
#define NCI 16
#define NCO 16
#define G_DIM 75
#define TILE_T 512   // t-elements per block (64 lanes x 8)

typedef float v4f __attribute__((ext_vector_type(4)));

// Inverse of ALL_IDX: for each original joint j, the output g-positions that
// replicate it (conv kernel height is 1, so gathered rows are pure copies).
__device__ const int d_nrep[J_DIM] = {4,3,3,3,3,3,3,3,3,5,3,3,3,3,3,3,3,3,3,3,3,3,3,3};
__device__ const int d_repl[J_DIM][5] = {
  {0, 9, 12, 15, -1},
  {1, 10, 18, -1, -1},
  {2, 13, 21, -1, -1},
  {3, 16, 24, -1, -1},
  {11, 19, 27, -1, -1},
  {14, 22, 30, -1, -1},
  {17, 25, 33, -1, -1},
  {20, 28, 38, -1, -1},
  {23, 31, 40, -1, -1},
  {26, 34, 42, 45, 48},
  {4, 29, 39, -1, -1},
  {5, 32, 41, -1, -1},
  {35, 43, 51, -1, -1},
  {36, 46, 53, -1, -1},
  {37, 49, 56, -1, -1},
  {6, 44, 52, -1, -1},
  {47, 54, 59, -1, -1},
  {50, 57, 62, -1, -1},
  {55, 60, 65, -1, -1},
  {58, 63, 68, -1, -1},
  {61, 66, 71, -1, -1},
  {64, 69, 73, -1, -1},
  {7, 67, 72, -1, -1},
  {8, 70, 74, -1, -1},
};

__global__ __launch_bounds__(256, 4) void skel_conv(
    const float* __restrict__ x, const float* __restrict__ W,
    const float* __restrict__ bias, float* __restrict__ out) {
  const int tile = blockIdx.x;   // t-tile (8 tiles of 512)
  const int j    = blockIdx.y;   // original joint
  const int b    = blockIdx.z;   // batch
  const int tid  = (int)threadIdx.x;
  const int lane = tid & 63;
  // wave id in SGPR -> all W/bias/out-channel indexing is provably uniform
  // -> s_load on the scalar pipe, no LDS, SGPR operands in the FMAs.
  const int wv  = __builtin_amdgcn_readfirstlane(tid >> 6);
  const int co0 = wv * 4;       // this wave handles co0..co0+3

  const int t0 = tile * TILE_T + lane * 8;

  // acc[cc] segments 0/1 for co = co0+cc, initialized with bias
  float4 acc0[4], acc1[4];
#pragma unroll
  for (int cc = 0; cc < 4; ++cc) {
    const float bb = bias[co0 + cc];
    acc0[cc] = make_float4(bb, bb, bb, bb);
    acc1[cc] = make_float4(bb, bb, bb, bb);
  }

  const float* __restrict__ Wg = W + (size_t)co0 * NCI * 3;

#pragma unroll 2
  for (int ci = 0; ci < NCI; ++ci) {
    const float* xp = x + (((size_t)b * NCI + ci) * J_DIM + j) * T_DIM;
    const float4 v0 = *(const float4*)(xp + t0);
    const float4 v1 = *(const float4*)(xp + t0 + 4);
    // t-halo via in-wave shuffle; wave-edge lanes patch with a direct load
    float xm1 = __shfl_up(v1.w, 1);    // x[t0-1]
    float xp8 = __shfl_down(v0.x, 1);  // x[t0+8]
    if (lane == 0)  xm1 = (t0 > 0) ? xp[t0 - 1] : 0.f;
    if (lane == 63) xp8 = (t0 + 8 < T_DIM) ? xp[t0 + 8] : 0.f;

#pragma unroll
    for (int cc = 0; cc < 4; ++cc) {
      const float w0 = Wg[(cc * NCI + ci) * 3 + 0];
      const float w1 = Wg[(cc * NCI + ci) * 3 + 1];
      const float w2 = Wg[(cc * NCI + ci) * 3 + 2];
      acc0[cc].x = fmaf(xm1,  w0, fmaf(v0.x, w1, fmaf(v0.y, w2, acc0[cc].x)));
      acc0[cc].y = fmaf(v0.x, w0, fmaf(v0.y, w1, fmaf(v0.z, w2, acc0[cc].y)));
      acc0[cc].z = fmaf(v0.y, w0, fmaf(v0.z, w1, fmaf(v0.w, w2, acc0[cc].z)));
      acc0[cc].w = fmaf(v0.z, w0, fmaf(v0.w, w1, fmaf(v1.x, w2, acc0[cc].w)));
      acc1[cc].x = fmaf(v0.w, w0, fmaf(v1.x, w1, fmaf(v1.y, w2, acc1[cc].x)));
      acc1[cc].y = fmaf(v1.x, w0, fmaf(v1.y, w1, fmaf(v1.z, w2, acc1[cc].y)));
      acc1[cc].z = fmaf(v1.y, w0, fmaf(v1.z, w1, fmaf(v1.w, w2, acc1[cc].z)));
      acc1[cc].w = fmaf(v1.z, w0, fmaf(v1.w, w1, fmaf(xp8,  w2, acc1[cc].w)));
    }
  }

  // Replicate to all gather positions. Nontemporal stores: output is
  // single-touch -> keep the 629MB write stream from evicting x in L2.
  const int nrep = d_nrep[j];
  for (int r = 0; r < nrep; ++r) {
    const int g = d_repl[j][r];
    float* op = out + (((size_t)b * NCO + co0) * G_DIM + g) * T_DIM + t0;
#pragma unroll
    for (int cc = 0; cc < 4; ++cc) {
      float* p = op + (size_t)cc * (G_DIM * T_DIM);
      __builtin_nontemporal_store(*(const v4f*)&acc0[cc], (v4f*)p);
      __builtin_nontemporal_store(*(const v4f*)&acc1[cc], (v4f*)(p + 4));
    }
  }
}

extern "C" void kernel_launch(void* const* d_in, const int* in_sizes, int n_in,
                              void* d_out, int out_size, void* d_ws, size_t ws_size,
                              hipStream_t stream) {
  const float* x    = (const float*)d_in[0];
  const float* W    = (const float*)d_in[1];
  const float* bias = (const float*)d_in[2];
  float* out = (float*)d_out;

  dim3 grid(T_DIM / TILE_T, J_DIM, 32);  // 8 x 24 x 32 = 6144 blocks
  dim3 block(256);
  skel_conv<<<grid, block, 0, stream>>>(x, W, bias, out);
}

// Round 8
// 181.939 us; speedup vs baseline: 1.4182x; 1.4182x over previous
//
#include <hip/hip_runtime.h>

#define T_DIM 4096
#define J_DIM 24
#define NCI 16
#define NCO 16
#define G_DIM 75
#define WAVE_T 256            // t-elements per wave (64 lanes x 4)
#define TILE_T (WAVE_T * 4)   // t-elements per block (4 waves)

// Inverse of ALL_IDX: for each original joint j, the output g-positions that
// replicate it (conv kernel height is 1, so gathered rows are pure copies).
__device__ const int d_nrep[J_DIM] = {4,3,3,3,3,3,3,3,3,5,3,3,3,3,3,3,3,3,3,3,3,3,3,3};
__device__ const int d_repl[J_DIM][5] = {
  {0, 9, 12, 15, -1},
  {1, 10, 18, -1, -1},
  {2, 13, 21, -1, -1},
  {3, 16, 24, -1, -1},
  {11, 19, 27, -1, -1},
  {14, 22, 30, -1, -1},
  {17, 25, 33, -1, -1},
  {20, 28, 38, -1, -1},
  {23, 31, 40, -1, -1},
  {26, 34, 42, 45, 48},
  {4, 29, 39, -1, -1},
  {5, 32, 41, -1, -1},
  {35, 43, 51, -1, -1},
  {36, 46, 53, -1, -1},
  {37, 49, 56, -1, -1},
  {6, 44, 52, -1, -1},
  {47, 54, 59, -1, -1},
  {50, 57, 62, -1, -1},
  {55, 60, 65, -1, -1},
  {58, 63, 68, -1, -1},
  {61, 66, 71, -1, -1},
  {64, 69, 73, -1, -1},
  {7, 67, 72, -1, -1},
  {8, 70, 74, -1, -1},
};

__global__ __launch_bounds__(256, 4) void skel_conv(
    const float* __restrict__ x, const float* __restrict__ W,
    const float* __restrict__ bias, float* __restrict__ out) {
  const int tile = blockIdx.x;   // block t-tile (4 tiles of 1024)
  const int j    = blockIdx.y;   // original joint
  const int b    = blockIdx.z;   // batch
  const int tid  = (int)threadIdx.x;
  const int lane = tid & 63;
  // Each WAVE owns a private 256-t slice and computes ALL 16 out-channels.
  // -> no two waves anywhere read the same x cache line (no intra-block
  //    re-fetch after L2 eviction by the write stream).
  const int wv = __builtin_amdgcn_readfirstlane(tid >> 6);

  const int t0 = tile * TILE_T + wv * WAVE_T + lane * 4;

  // acc[co], initialized with bias (block-uniform scalar loads)
  float4 acc[NCO];
#pragma unroll
  for (int co = 0; co < NCO; ++co) {
    const float bb = bias[co];
    acc[co] = make_float4(bb, bb, bb, bb);
  }

#pragma unroll 2
  for (int ci = 0; ci < NCI; ++ci) {
    const float* xp = x + (((size_t)b * NCI + ci) * J_DIM + j) * T_DIM;
    const float4 v = *(const float4*)(xp + t0);
    // t-halo via in-wave shuffle; wave-edge lanes patch with a direct load
    float xm1 = __shfl_up(v.w, 1);    // x[t0-1]
    float xp4 = __shfl_down(v.x, 1);  // x[t0+4]
    if (lane == 0)  xm1 = (t0 > 0) ? xp[t0 - 1] : 0.f;
    if (lane == 63) xp4 = (t0 + 4 < T_DIM) ? xp[t0 + 4] : 0.f;

#pragma unroll
    for (int co = 0; co < NCO; ++co) {
      // uniform indices -> s_load; SGPR operands in the FMAs
      const float w0 = W[(co * NCI + ci) * 3 + 0];
      const float w1 = W[(co * NCI + ci) * 3 + 1];
      const float w2 = W[(co * NCI + ci) * 3 + 2];
      acc[co].x = fmaf(xm1, w0, fmaf(v.x, w1, fmaf(v.y, w2, acc[co].x)));
      acc[co].y = fmaf(v.x, w0, fmaf(v.y, w1, fmaf(v.z, w2, acc[co].y)));
      acc[co].z = fmaf(v.y, w0, fmaf(v.z, w1, fmaf(v.w, w2, acc[co].z)));
      acc[co].w = fmaf(v.z, w0, fmaf(v.w, w1, fmaf(xp4, w2, acc[co].w)));
    }
  }

  // replicate this joint's conv result to all its gather positions
  const int nrep = d_nrep[j];
  for (int r = 0; r < nrep; ++r) {
    const int g = d_repl[j][r];
    float* op = out + ((size_t)b * NCO * G_DIM + g) * T_DIM + t0;
#pragma unroll
    for (int co = 0; co < NCO; ++co) {
      *(float4*)(op + (size_t)co * (G_DIM * T_DIM)) = acc[co];
    }
  }
}

extern "C" void kernel_launch(void* const* d_in, const int* in_sizes, int n_in,
                              void* d_out, int out_size, void* d_ws, size_t ws_size,
                              hipStream_t stream) {
  const float* x    = (const float*)d_in[0];
  const float* W    = (const float*)d_in[1];
  const float* bias = (const float*)d_in[2];
  float* out = (float*)d_out;

  dim3 grid(T_DIM / TILE_T, J_DIM, 32);  // 4 x 24 x 32 = 3072 blocks
  dim3 block(256);
  skel_conv<<<grid, block, 0, stream>>>(x, W, bias, out);
}